// Round 9
// baseline (21.238 us; speedup 1.0000x reference)
//
#include <hip/hip_runtime.h>

#define NJ   24
#define BLK  256
#define JREC 5                  // float4 slots per joint record (4 data + 1 pad)
#define QMF4 (NJ * JREC)        // float4 index of (Qm) ; +1 = pm
#define NCPY (NJ * JREC + 2)    // float4s in the LDS constant table
#define INV4PI 0.07957747154594767f

// SE(3) element as unit quaternion + translation.
struct DQ { float w, x, y, z, t0, t1, t2; };

// Compose C = A * B  (rotation: A.q (x) B.q ; translation: A.t + rot(A.q, B.t))
__device__ __forceinline__ DQ dq_comp(const DQ A, const DQ B) {
    const float u10 = A.y*B.t2 - A.z*B.t1;
    const float u11 = A.z*B.t0 - A.x*B.t2;
    const float u12 = A.x*B.t1 - A.y*B.t0;
    const float u20 = A.y*u12 - A.z*u11;
    const float u21 = A.z*u10 - A.x*u12;
    const float u22 = A.x*u11 - A.y*u10;
    const float tw  = 2.0f * A.w;
    DQ C;
    C.t0 = fmaf(tw, u10, fmaf(2.0f, u20, A.t0 + B.t0));
    C.t1 = fmaf(tw, u11, fmaf(2.0f, u21, A.t1 + B.t1));
    C.t2 = fmaf(tw, u12, fmaf(2.0f, u22, A.t2 + B.t2));
    C.w = A.w*B.w - A.x*B.x - A.y*B.y - A.z*B.z;
    C.x = A.w*B.x + A.x*B.w + A.y*B.z - A.z*B.y;
    C.y = A.w*B.y - A.x*B.z + A.y*B.w + A.z*B.x;
    C.z = A.w*B.z + A.x*B.y - A.y*B.x + A.z*B.w;
    return C;
}

// Build exp(a * xi_j) from the joint record (4 float4s) and angle a.
__device__ __forceinline__ DQ dq_exp(const float4 A4, const float4 B4,
                                     const float4 C4, const float4 D4,
                                     const float a) {
    const float hrev = a * B4.w;                  // phi/(4*pi): half-angle revs
    const float sh   = __builtin_amdgcn_sinf(hrev);
    const float ch   = __builtin_amdgcn_cosf(hrev);
    const float s    = 2.0f * sh * ch;            // sin(phi)
    const float cB   = 2.0f * sh * sh;            // 1 - cos(phi)
    const float phi  = a * A4.w;
    const float g    = phi - s;
    DQ e;
    e.w  = ch;
    e.x  = sh * A4.x;
    e.y  = sh * A4.y;
    e.z  = sh * A4.z;
    e.t0 = fmaf(a, B4.x, fmaf(cB, C4.x, g * D4.x));
    e.t1 = fmaf(a, B4.y, fmaf(cB, C4.y, g * D4.y));
    e.t2 = fmaf(a, B4.z, fmaf(cB, C4.z, g * D4.z));
    return e;
}

// ---------------------------------------------------------------------------
// Fused kernel. Block prep: threads 0..23 build joint records in LDS, thread
// 24 builds exp(M) as (quat, trans). Then 4 lanes per batch row: lane q owns
// joints 6q..6q+5, builds the 6 exponentials INDEPENDENTLY (sin/cos latencies
// overlap) and combines them as a tree: (e0 e1)(e2 e3)(e4 e5) -> depth 3,
// then 2 __shfl_xor rounds across the quad, fold exp(M), Q->R, and each lane
// stores one 16B row of T (fully coalesced).
// ---------------------------------------------------------------------------
__global__ __launch_bounds__(BLK, 4)
void poe_main(const float* __restrict__ x,
              const float* __restrict__ eta,
              const float* __restrict__ M,
              float* __restrict__ out,
              int nBatch)
{
    __shared__ float4 sC[NCPY];
    float* sF = (float*)sC;

    const int t = threadIdx.x;
    if (t < NJ) {
        const float w0 = eta[t*6+0], w1 = eta[t*6+1], w2 = eta[t*6+2];
        const float v0 = eta[t*6+3], v1 = eta[t*6+4], v2 = eta[t*6+5];
        const float k  = w0*w0 + w1*w1 + w2*w2;
        const bool  sm = (k < 1e-12f);
        const float invsqk = sm ? 0.0f : rsqrtf(k);
        const float sqk    = k * invsqk;
        const float invk   = invsqk * invsqk;
        const float invk15 = invk * invsqk;
        const float c10 = w1*v2 - w2*v1;
        const float c11 = w2*v0 - w0*v2;
        const float c12 = w0*v1 - w1*v0;
        const float c20 = w1*c12 - w2*c11;
        const float c21 = w2*c10 - w0*c12;
        const float c22 = w0*c11 - w1*c10;
        float* r = sF + t * JREC * 4;
        r[0]  = w0*invsqk;  r[1]  = w1*invsqk;  r[2]  = w2*invsqk;  r[3]  = sqk;
        r[4]  = v0;         r[5]  = v1;         r[6]  = v2;         r[7]  = sqk * INV4PI;
        r[8]  = c10*invk;   r[9]  = c11*invk;   r[10] = c12*invk;   r[11] = 0.0f;
        r[12] = c20*invk15; r[13] = c21*invk15; r[14] = c22*invk15; r[15] = 0.0f;
    } else if (t == NJ) {
        const float w0 = M[0], w1 = M[1], w2 = M[2];
        const float v0 = M[3], v1 = M[4], v2 = M[5];
        const float t2 = w0*w0 + w1*w1 + w2*w2;
        const bool  sm = (t2 < 1e-12f);
        const float t2s  = sm ? 1.0f : t2;
        const float invt = rsqrtf(t2s);
        const float th   = t2s * invt;
        float s, c;
        __sincosf(th, &s, &c);
        const float invt2 = invt * invt;
        const float B = sm ? 0.5f        : (1.0f - c) * invt2;
        const float C = sm ? (1.0f/6.0f) : (th - s) * invt2 * invt;
        float sh, chh;
        __sincosf(0.5f * th, &sh, &chh);
        const float axs = sm ? 0.5f : sh * invt;   // sin(th/2)/th (limit 1/2)
        float* r = sF + QMF4 * 4;
        r[0] = sm ? 1.0f : chh;
        r[1] = axs * w0;
        r[2] = axs * w1;
        r[3] = axs * w2;
        const float c10 = w1*v2 - w2*v1, c11 = w2*v0 - w0*v2, c12 = w0*v1 - w1*v0;
        const float c20 = w1*c12 - w2*c11, c21 = w2*c10 - w0*c12, c22 = w0*c11 - w1*c10;
        r[4] = v0 + B*c10 + C*c20;
        r[5] = v1 + B*c11 + C*c21;
        r[6] = v2 + B*c12 + C*c22;
        r[7] = 0.0f;
    }

    // ---- own 6 joint angles (independent of LDS prep; issue before sync) ----
    const int gid = blockIdx.x * BLK + t;
    const int row = gid >> 2;
    const int q   = gid & 3;
    const bool active = row < nBatch;

    float2 xa = make_float2(0.f,0.f), xb = xa, xc = xa;
    if (active) {
        const float2* xp = (const float2*)(x + (size_t)row * NJ + q * 6);
        xa = xp[0]; xb = xp[1]; xc = xp[2];
    }

    __syncthreads();

    const int cbase = q * 6 * JREC;   // float4 index of this lane's first record

#define REC(JJ, S) sC[cbase + (JJ)*JREC + (S)]

    // ---- build 6 exponentials independently, tree-combine (depth 3) ----
    const DQ e0 = dq_exp(REC(0,0), REC(0,1), REC(0,2), REC(0,3), xa.x);
    const DQ e1 = dq_exp(REC(1,0), REC(1,1), REC(1,2), REC(1,3), xa.y);
    const DQ e2 = dq_exp(REC(2,0), REC(2,1), REC(2,2), REC(2,3), xb.x);
    const DQ e3 = dq_exp(REC(3,0), REC(3,1), REC(3,2), REC(3,3), xb.y);
    const DQ e4 = dq_exp(REC(4,0), REC(4,1), REC(4,2), REC(4,3), xc.x);
    const DQ e5 = dq_exp(REC(5,0), REC(5,1), REC(5,2), REC(5,3), xc.y);
#undef REC

    const DQ c01 = dq_comp(e0, e1);
    const DQ c23 = dq_comp(e2, e3);
    const DQ c45 = dq_comp(e4, e5);
    const DQ c03 = dq_comp(c01, c23);
    DQ T = dq_comp(c03, c45);

    // ---- combine within the quad: rounds xor-1, xor-2 ----
#define COMBINE(BIT) do {                                                     \
    DQ O;                                                                     \
    O.w  = __shfl_xor(T.w,  BIT);  O.x  = __shfl_xor(T.x,  BIT);              \
    O.y  = __shfl_xor(T.y,  BIT);  O.z  = __shfl_xor(T.z,  BIT);              \
    O.t0 = __shfl_xor(T.t0, BIT);  O.t1 = __shfl_xor(T.t1, BIT);              \
    O.t2 = __shfl_xor(T.t2, BIT);                                             \
    const bool up = (q & (BIT)) != 0;   /* self is the SECOND factor */       \
    DQ A, B;                                                                  \
    A.w  = up ? O.w  : T.w;   B.w  = up ? T.w  : O.w;                         \
    A.x  = up ? O.x  : T.x;   B.x  = up ? T.x  : O.x;                         \
    A.y  = up ? O.y  : T.y;   B.y  = up ? T.y  : O.y;                         \
    A.z  = up ? O.z  : T.z;   B.z  = up ? T.z  : O.z;                         \
    A.t0 = up ? O.t0 : T.t0;  B.t0 = up ? T.t0 : O.t0;                        \
    A.t1 = up ? O.t1 : T.t1;  B.t1 = up ? T.t1 : O.t1;                        \
    A.t2 = up ? O.t2 : T.t2;  B.t2 = up ? T.t2 : O.t2;                        \
    T = dq_comp(A, B);                                                        \
} while (0)

    COMBINE(1);
    COMBINE(2);
#undef COMBINE

    // ---- fold exp(M): T = T * Em ----
    {
        const float4 Qm = sC[QMF4];
        const float4 Pm = sC[QMF4 + 1];
        DQ Em;
        Em.w = Qm.x; Em.x = Qm.y; Em.y = Qm.z; Em.z = Qm.w;
        Em.t0 = Pm.x; Em.t1 = Pm.y; Em.t2 = Pm.z;
        T = dq_comp(T, Em);
    }

    // ---- Q -> R, pick my row, store (coalesced 16B/lane) ----
    if (active) {
        const float xx = T.x*T.x, yy = T.y*T.y, zz = T.z*T.z;
        const float xy = T.x*T.y, xz = T.x*T.z, yz = T.y*T.z;
        const float wx = T.w*T.x, wy = T.w*T.y, wz = T.w*T.z;
        const float R00 = 1.0f - 2.0f*(yy + zz);
        const float R01 = 2.0f*(xy - wz);
        const float R02 = 2.0f*(xz + wy);
        const float R10 = 2.0f*(xy + wz);
        const float R11 = 1.0f - 2.0f*(xx + zz);
        const float R12 = 2.0f*(yz - wx);
        const float R20 = 2.0f*(xz - wy);
        const float R21 = 2.0f*(yz + wx);
        const float R22 = 1.0f - 2.0f*(xx + yy);

        float4 mine;
        if      (q == 0) mine = make_float4(R00, R01, R02, T.t0);
        else if (q == 1) mine = make_float4(R10, R11, R12, T.t1);
        else if (q == 2) mine = make_float4(R20, R21, R22, T.t2);
        else             mine = make_float4(0.0f, 0.0f, 0.0f, 1.0f);

        ((float4*)out)[(size_t)row * 4 + q] = mine;
    }
}

extern "C" void kernel_launch(void* const* d_in, const int* in_sizes, int n_in,
                              void* d_out, int out_size, void* d_ws, size_t ws_size,
                              hipStream_t stream)
{
    const float* x   = (const float*)d_in[0];
    const float* eta = (const float*)d_in[1];
    const float* M   = (const float*)d_in[2];
    float* out = (float*)d_out;

    const int nBatch   = in_sizes[0] / NJ;
    const int nThreads = nBatch * 4;
    const int grid     = (nThreads + BLK - 1) / BLK;

    poe_main<<<grid, BLK, 0, stream>>>(x, eta, M, out, nBatch);
}